// Round 6
// baseline (6178.823 us; speedup 1.0000x reference)
//
#include <hip/hip_runtime.h>
#include <cstdint>

#define BATCH   4
#define NPTS    16384
#define NCH     64
#define NPOINT  2048
#define NSAMP   32

// output layout (floats), concatenated in reference return order
#define OFF_XYZ  0                                 // new_xyz      (B,S,3)
#define OFF_IDX1 (BATCH*NPOINT*3)                  // new_xyz_idx  (B,S)    as float
#define OFF_FEAT (OFF_IDX1 + BATCH*NPOINT)         // new_features (B,128,S)
#define OFF_IDX3 (OFF_FEAT + BATCH*128*NPOINT)     // idx          (B,S,32) as float

// Scratch for sorted points lives in the new_features region of d_out
// (1,048,576 floats); mlp_kernel fully overwrites it afterwards.

// Exact float32 squared distance in numpy's evaluation order.
__device__ __forceinline__ float sqd_exact(float dx, float dy, float dz) {
    float a = __fmul_rn(dx, dx);
    float b = __fmul_rn(dy, dy);
    float c = __fmul_rn(dz, dz);
    return __fadd_rn(__fadd_rn(a, b), c);
}

__device__ __forceinline__ int part3(int v) {
    return (v & 1) | ((v & 2) << 2) | ((v & 4) << 4) | ((v & 8) << 6);
}

// Wave64 max of a NONNEGATIVE float via DPP (no LDS). Result broadcast via
// readlane(63). old=0 is the identity since all inputs are >= 0.
// (Validated bit-exact in rounds 4/5: absmax 0.)
__device__ __forceinline__ float wave_max_nonneg(float x) {
    int v;
    v = __builtin_amdgcn_update_dpp(0, __float_as_int(x), 0x111, 0xf, 0xf, false); // row_shr:1
    x = fmaxf(x, __int_as_float(v));
    v = __builtin_amdgcn_update_dpp(0, __float_as_int(x), 0x112, 0xf, 0xf, false); // row_shr:2
    x = fmaxf(x, __int_as_float(v));
    v = __builtin_amdgcn_update_dpp(0, __float_as_int(x), 0x114, 0xf, 0xf, false); // row_shr:4
    x = fmaxf(x, __int_as_float(v));
    v = __builtin_amdgcn_update_dpp(0, __float_as_int(x), 0x118, 0xf, 0xf, false); // row_shr:8
    x = fmaxf(x, __int_as_float(v));
    v = __builtin_amdgcn_update_dpp(0, __float_as_int(x), 0x142, 0xa, 0xf, false); // row_bcast:15
    x = fmaxf(x, __int_as_float(v));
    v = __builtin_amdgcn_update_dpp(0, __float_as_int(x), 0x143, 0xc, 0xf, false); // row_bcast:31
    x = fmaxf(x, __int_as_float(v));
    return __int_as_float(__builtin_amdgcn_readlane(__float_as_int(x), 63));
}

// ---------------------------------------------------------------------------
// Kernel 0: Morton-bin counting sort (per batch).
// ---------------------------------------------------------------------------
__global__ __launch_bounds__(1024)
void binsort_kernel(const float* __restrict__ xyz, float* __restrict__ out) {
    const int b = blockIdx.x, t = threadIdx.x, lane = t & 63, wv = t >> 6;
    float* scr  = out + OFF_FEAT;
    float* sx   = scr + (size_t)b * NPTS;
    float* sy   = scr + (size_t)(BATCH + b) * NPTS;
    float* sz   = scr + (size_t)(2 * BATCH + b) * NPTS;
    int*   sidx = (int*)(scr + (size_t)3 * BATCH * NPTS) + (size_t)b * NPTS;
    const float* xb = xyz + (size_t)b * (NPTS * 3);

    __shared__ int hist[4096];
    __shared__ int wsum[16];
    for (int k = t; k < 4096; k += 1024) hist[k] = 0;
    __syncthreads();

    const int base = t << 4;
    float f[48];
    {
        const float4* v4 = (const float4*)(xb + (size_t)base * 3);
#pragma unroll
        for (int q = 0; q < 12; ++q) {
            float4 v = v4[q];
            f[4*q+0] = v.x; f[4*q+1] = v.y; f[4*q+2] = v.z; f[4*q+3] = v.w;
        }
    }
    int cells[16];
    const float sc = 16.0f / 9.0f;
#pragma unroll
    for (int j = 0; j < 16; ++j) {
        int qx = (int)fminf(fmaxf((f[3*j+0] + 4.5f) * sc, 0.0f), 15.0f);
        int qy = (int)fminf(fmaxf((f[3*j+1] + 4.5f) * sc, 0.0f), 15.0f);
        int qz = (int)fminf(fmaxf((f[3*j+2] + 4.5f) * sc, 0.0f), 15.0f);
        cells[j] = part3(qx) | (part3(qy) << 1) | (part3(qz) << 2);
        atomicAdd(&hist[cells[j]], 1);
    }
    __syncthreads();

    int h0 = hist[4*t], h1 = hist[4*t+1], h2 = hist[4*t+2], h3 = hist[4*t+3];
    int s = h0 + h1 + h2 + h3;
    int ps = s;
#pragma unroll
    for (int off = 1; off <= 32; off <<= 1) {
        int o = __shfl_up(ps, off, 64);
        if (lane >= off) ps += o;
    }
    if (lane == 63) wsum[wv] = ps;
    __syncthreads();
    int wbase = 0;
    for (int w = 0; w < wv; ++w) wbase += wsum[w];
    int excl = wbase + ps - s;
    hist[4*t]   = excl;
    hist[4*t+1] = excl + h0;
    hist[4*t+2] = excl + h0 + h1;
    hist[4*t+3] = excl + h0 + h1 + h2;
    __syncthreads();

#pragma unroll
    for (int j = 0; j < 16; ++j) {
        int pos = atomicAdd(&hist[cells[j]], 1);
        sx[pos] = f[3*j+0]; sy[pos] = f[3*j+1]; sz[pos] = f[3*j+2];
        sidx[pos] = base + j;
    }
}

// ---------------------------------------------------------------------------
// Kernel 1: exact bucket-pruned FPS.
// R5 winner + two surgical changes:
//  (a) u32 keys (f32 distbits) -> post-barrier scan is 4 x ds_read_b128
//      instead of 16 x ds_read_b64; exact tie via rare aux path.
//  (b) winner coords travel through LDS: mk packs (~bi)<<16|bj; the elected
//      leader selects px[bj]/py[bj]/pz[bj] by unrolled cndmask and writes
//      float4{x,y,z,aux} -> no global center load on the serial chain.
// Update loop is R2/R5-verbatim (no coord tracking => no spill pressure).
// ---------------------------------------------------------------------------
__global__ __launch_bounds__(1024)
void fps_kernel(const float* __restrict__ xyz, float* __restrict__ out) {
    const int b = blockIdx.x, t = threadIdx.x, wv = t >> 6;
    const float* scr  = out + OFF_FEAT;
    const float* sxp  = scr + (size_t)b * NPTS;
    const float* syp  = scr + (size_t)(BATCH + b) * NPTS;
    const float* szp  = scr + (size_t)(2 * BATCH + b) * NPTS;
    const int*   sip  = (const int*)(scr + (size_t)3 * BATCH * NPTS) + (size_t)b * NPTS;
    const float* __restrict__ xb = xyz + (size_t)b * (NPTS * 3);
    float* oxyz = out + OFF_XYZ  + (size_t)b * (NPOINT * 3);
    float* oidx = out + OFF_IDX1 + (size_t)b * NPOINT;

    const int base = t << 4;
    float px[16], py[16], pz[16], dist[16];
    unsigned idx2[8];
    {
        const float4* vx = (const float4*)(sxp + base);
        const float4* vy = (const float4*)(syp + base);
        const float4* vz = (const float4*)(szp + base);
        const int4*   vi = (const int4*)(sip + base);
#pragma unroll
        for (int q = 0; q < 4; ++q) {
            float4 a = vx[q]; px[4*q] = a.x; px[4*q+1] = a.y; px[4*q+2] = a.z; px[4*q+3] = a.w;
            float4 c = vy[q]; py[4*q] = c.x; py[4*q+1] = c.y; py[4*q+2] = c.z; py[4*q+3] = c.w;
            float4 d = vz[q]; pz[4*q] = d.x; pz[4*q+1] = d.y; pz[4*q+2] = d.z; pz[4*q+3] = d.w;
            int4   i = vi[q];
            idx2[2*q]   = (unsigned)i.x | ((unsigned)i.y << 16);
            idx2[2*q+1] = (unsigned)i.z | ((unsigned)i.w << 16);
        }
    }
    float bnx = px[0], bxx = px[0], bny = py[0], bxy = py[0], bnz = pz[0], bxz = pz[0];
#pragma unroll
    for (int j = 1; j < 16; ++j) {
        bnx = fminf(bnx, px[j]); bxx = fmaxf(bxx, px[j]);
        bny = fminf(bny, py[j]); bxy = fmaxf(bxy, py[j]);
        bnz = fminf(bnz, pz[j]); bxz = fmaxf(bxz, pz[j]);
    }
#pragma unroll
    for (int j = 0; j < 16; ++j) dist[j] = 1e10f;
    // mk = distbits<<32 | (~bi & 0xFFFF)<<16 | bj   (bi unique => mk unique)
    unsigned long long mk = 0;
    float maxdG = 1e30f;            // forces all buckets active at it=1

    __shared__ __align__(16) unsigned s_key[2][16];
    __shared__ __align__(16) float4   s_coord[2][16];

    float cx = xb[0], cy = xb[1], cz = xb[2];
    if (t == 0) { oxyz[0] = cx; oxyz[1] = cy; oxyz[2] = cz; oidx[0] = 0.0f; }

    for (int it = 1; it < NPOINT; ++it) {
        const int q = it & 1;
        float dxl = fmaxf(fmaxf(bnx - cx, cx - bxx), 0.0f);
        float dyl = fmaxf(fmaxf(bny - cy, cy - bxy), 0.0f);
        float dzl = fmaxf(fmaxf(bnz - cz, cz - bxz), 0.0f);
        float bb  = dxl * dxl + dyl * dyl + dzl * dzl;
        if (bb * 0.99999f < maxdG) {          // bucket must update (exact test)
            float mv = 0.0f;
#pragma unroll
            for (int j = 0; j < 16; ++j) {
                float d  = sqd_exact(__fsub_rn(px[j], cx),
                                     __fsub_rn(py[j], cy),
                                     __fsub_rn(pz[j], cz));
                float nd = fminf(dist[j], d);
                dist[j] = nd;
                mv = fmaxf(mv, nd);
            }
            int bi = 0xFFFF, bj = 0;          // min orig idx among value-ties
#pragma unroll
            for (int j = 0; j < 16; ++j) {
                int oi = (int)((idx2[j >> 1] >> ((j & 1) * 16)) & 0xFFFFu);
                bool e = (dist[j] == mv) & (oi < bi);
                bi = e ? oi : bi;
                bj = e ? j  : bj;
            }
            mk = ((unsigned long long)__float_as_uint(mv) << 32)
               | ((unsigned long long)((~bi) & 0xFFFFu) << 16)
               | (unsigned)bj;
            maxdG = mv;
        }
        // wave max via DPP (VALU only) + ballot leader election
        float wm = wave_max_nonneg(maxdG);
        bool cand = (maxdG == wm);
        unsigned long long msk = __ballot(cand);
        if (__popcll(msk) > 1) {              // exact rare in-wave tie path
            unsigned long long best = 0;
            unsigned long long m2 = msk;
            while (m2) {
                int l = __ffsll(m2) - 1;
                unsigned long long omk = __shfl(mk, l, 64);
                best = best > omk ? best : omk;    // max mk == min orig idx
                m2 &= m2 - 1;
            }
            cand = cand && (mk == best);      // mk unique -> unique leader
        }
        if (cand) {                           // leader writes key + coords
            const int bj = (int)(mk & 0xFu);
            float sx_ = px[0], sy_ = py[0], sz_ = pz[0];
#pragma unroll
            for (int j = 1; j < 16; ++j) {
                bool e = (bj == j);
                sx_ = e ? px[j] : sx_;
                sy_ = e ? py[j] : sy_;
                sz_ = e ? pz[j] : sz_;
            }
            s_key[q][wv]   = (unsigned)(mk >> 32);
            s_coord[q][wv] = make_float4(sx_, sy_, sz_,
                                         __uint_as_float((unsigned)mk));
        }
        __syncthreads();
        // all threads: 16 u32 keys as 4 x b128, register argmax
        const uint4* kp = (const uint4*)&s_key[q][0];
        uint4 A = kp[0], B = kp[1], C = kp[2], D = kp[3];
        unsigned bk = A.x; int bw = 0;
#define CMP_K(val, idx) { bool g = (val) > bk; bk = g ? (val) : bk; bw = g ? (idx) : bw; }
        CMP_K(A.y, 1)  CMP_K(A.z, 2)  CMP_K(A.w, 3)
        CMP_K(B.x, 4)  CMP_K(B.y, 5)  CMP_K(B.z, 6)  CMP_K(B.w, 7)
        CMP_K(C.x, 8)  CMP_K(C.y, 9)  CMP_K(C.z, 10) CMP_K(C.w, 11)
        CMP_K(D.x, 12) CMP_K(D.y, 13) CMP_K(D.z, 14) CMP_K(D.w, 15)
#undef CMP_K
        int cnt = (A.x == bk) + (A.y == bk) + (A.z == bk) + (A.w == bk)
                + (B.x == bk) + (B.y == bk) + (B.z == bk) + (B.w == bk)
                + (C.x == bk) + (C.y == bk) + (C.z == bk) + (C.w == bk)
                + (D.x == bk) + (D.y == bk) + (D.z == bk) + (D.w == bk);
        if (cnt > 1) {                        // exact rare cross-wave tie
            unsigned bestAux = 0; int bw2 = bw;
            for (int i = 0; i < 16; ++i) {
                unsigned ki = s_key[q][i];
                if (ki == bk) {
                    unsigned aux = __float_as_uint(s_coord[q][i].w);
                    if (aux > bestAux) { bestAux = aux; bw2 = i; } // max aux = min bi
                }
            }
            bw = bw2;
        }
        float4 f = s_coord[q][bw];
        cx = f.x; cy = f.y; cz = f.z;
        if (t == 0) {
            unsigned aux = __float_as_uint(f.w);
            int gi = (int)((~(aux >> 16)) & 0xFFFFu);
            oxyz[it*3+0] = cx; oxyz[it*3+1] = cy; oxyz[it*3+2] = cz;
            oidx[it] = (float)gi;
        }
    }
}

// ---------------------------------------------------------------------------
// Kernel 2: ball query (unchanged).
// ---------------------------------------------------------------------------
__global__ __launch_bounds__(256)
void ballq_kernel(const float* __restrict__ xyz, float* __restrict__ out) {
    const int b    = blockIdx.y;
    const int t    = threadIdx.x;
    const int lane = t & 63;
    const int wv   = t >> 6;
    const int s    = blockIdx.x * 4 + wv;
    const float* __restrict__ xb = xyz + (size_t)b * (NPTS * 3);

    const float* ctr = out + OFF_XYZ + ((size_t)(b * NPOINT + s)) * 3;
    const float cx = ctr[0], cy = ctr[1], cz = ctr[2];

    __shared__ float sx[256], sy[256], sz[256];
    __shared__ int   lists[4][NSAMP];

    int have = 0;
    for (int tile = 0; tile < NPTS / 256; ++tile) {
        const int pi = tile * 256 + t;
        const float* p = xb + (size_t)pi * 3;
        float ax = p[0], ay = p[1], az = p[2];
        sx[t] = ax; sy[t] = ay; sz[t] = az;
        __syncthreads();
        if (have < NSAMP) {
#pragma unroll
            for (int sub = 0; sub < 4; ++sub) {
                const int li = sub * 64 + lane;
                float d2 = sqd_exact(__fsub_rn(cx, sx[li]),
                                     __fsub_rn(cy, sy[li]),
                                     __fsub_rn(cz, sz[li]));
                bool hit = d2 < 0.04f;
                unsigned long long m = __ballot(hit);
                if (hit) {
                    int pos = have + (int)__popcll(m & ((1ull << lane) - 1ull));
                    if (pos < NSAMP) lists[wv][pos] = tile * 256 + li;
                }
                have += (int)__popcll(m);
                if (have >= NSAMP) break;
            }
        }
        __syncthreads();
    }
    if (lane < NSAMP) {
        int hv = have < NSAMP ? have : NSAMP;
        int v0 = (have > 0) ? lists[wv][0] : 0;
        int v  = (lane < hv) ? lists[wv][lane] : v0;
        out[OFF_IDX3 + ((size_t)(b * NPOINT + s)) * NSAMP + lane] = (float)v;
    }
}

// ---------------------------------------------------------------------------
// Kernel 3: gather + 3-layer MLP + max over samples (unchanged).
// ---------------------------------------------------------------------------
__global__ __launch_bounds__(256)
void mlp_kernel(const float* __restrict__ xyz, const float* __restrict__ feat,
                const float* __restrict__ W1, const float* __restrict__ b1,
                const float* __restrict__ W2, const float* __restrict__ b2,
                const float* __restrict__ W3, const float* __restrict__ b3,
                float* __restrict__ out) {
    const int s = blockIdx.x;
    const int b = blockIdx.y;
    const int t = threadIdx.x;

    __shared__ __align__(16) float Wbuf[64 * 128];
    __shared__ float Xs[67 * 32];
    __shared__ float H1[64 * 32];
    __shared__ float H2[64 * 32];
    __shared__ int   idxs[NSAMP];
    __shared__ float ctr[3];

    if (t < NSAMP) idxs[t] = (int)out[OFF_IDX3 + ((size_t)(b * NPOINT + s)) * NSAMP + t];
    if (t < 3)     ctr[t]  = out[OFF_XYZ + ((size_t)(b * NPOINT + s)) * 3 + t];
    for (int k = t; k < 67 * 64; k += 256) {
        int i = k >> 6, o = k & 63;
        Wbuf[k] = W1[o * 67 + i];
    }
    __syncthreads();

    const float* xb = xyz  + (size_t)b * (NPTS * 3);
    const float* fb = feat + (size_t)b * (NCH * NPTS);
    for (int k = t; k < 67 * 32; k += 256) {
        int i = k >> 5, n = k & 31;
        int ii = idxs[n];
        float v;
        if (i < 3) v = __fsub_rn(xb[(size_t)ii * 3 + i], ctr[i]);
        else       v = fb[(size_t)(i - 3) * NPTS + ii];
        Xs[k] = v;
    }
    __syncthreads();

    const int n  = t & 31;
    const int og = t >> 5;

    {
        const int o0 = og * 8;
        float acc[8] = {0,0,0,0,0,0,0,0};
        for (int i = 0; i < 67; ++i) {
            float x = Xs[i * 32 + n];
            const float4* wp = (const float4*)&Wbuf[i * 64 + o0];
            float4 w0 = wp[0], w1 = wp[1];
            acc[0] += w0.x * x; acc[1] += w0.y * x; acc[2] += w0.z * x; acc[3] += w0.w * x;
            acc[4] += w1.x * x; acc[5] += w1.y * x; acc[6] += w1.z * x; acc[7] += w1.w * x;
        }
#pragma unroll
        for (int k = 0; k < 8; ++k)
            H1[(o0 + k) * 32 + n] = fmaxf(acc[k] + b1[o0 + k], 0.0f);
    }
    __syncthreads();
    for (int k = t; k < 64 * 64; k += 256) {
        int i = k >> 6, o = k & 63;
        Wbuf[k] = W2[o * 64 + i];
    }
    __syncthreads();

    {
        const int o0 = og * 8;
        float acc[8] = {0,0,0,0,0,0,0,0};
        for (int i = 0; i < 64; ++i) {
            float x = H1[i * 32 + n];
            const float4* wp = (const float4*)&Wbuf[i * 64 + o0];
            float4 w0 = wp[0], w1 = wp[1];
            acc[0] += w0.x * x; acc[1] += w0.y * x; acc[2] += w0.z * x; acc[3] += w0.w * x;
            acc[4] += w1.x * x; acc[5] += w1.y * x; acc[6] += w1.z * x; acc[7] += w1.w * x;
        }
#pragma unroll
        for (int k = 0; k < 8; ++k)
            H2[(o0 + k) * 32 + n] = fmaxf(acc[k] + b2[o0 + k], 0.0f);
    }
    __syncthreads();
    for (int k = t; k < 64 * 128; k += 256) {
        int i = k >> 7, o = k & 127;
        Wbuf[k] = W3[o * 64 + i];
    }
    __syncthreads();

    {
        const int o0 = og * 16;
        float acc[16];
#pragma unroll
        for (int k = 0; k < 16; ++k) acc[k] = 0.0f;
        for (int i = 0; i < 64; ++i) {
            float x = H2[i * 32 + n];
            const float4* wp = (const float4*)&Wbuf[i * 128 + o0];
            float4 w0 = wp[0], w1 = wp[1], w2 = wp[2], w3 = wp[3];
            acc[0]  += w0.x * x; acc[1]  += w0.y * x; acc[2]  += w0.z * x; acc[3]  += w0.w * x;
            acc[4]  += w1.x * x; acc[5]  += w1.y * x; acc[6]  += w1.z * x; acc[7]  += w1.w * x;
            acc[8]  += w2.x * x; acc[9]  += w2.y * x; acc[10] += w2.z * x; acc[11] += w2.w * x;
            acc[12] += w3.x * x; acc[13] += w3.y * x; acc[14] += w3.z * x; acc[15] += w3.w * x;
        }
#pragma unroll
        for (int k = 0; k < 16; ++k) {
            float h = fmaxf(acc[k] + b3[o0 + k], 0.0f);
#pragma unroll
            for (int off = 16; off >= 1; off >>= 1)
                h = fmaxf(h, __shfl_xor(h, off, 64));
            if (n == 0)
                out[OFF_FEAT + (size_t)b * 128 * NPOINT + (size_t)(o0 + k) * NPOINT + s] = h;
        }
    }
}

extern "C" void kernel_launch(void* const* d_in, const int* in_sizes, int n_in,
                              void* d_out, int out_size, void* d_ws, size_t ws_size,
                              hipStream_t stream) {
    const float* xyz  = (const float*)d_in[0];
    const float* feat = (const float*)d_in[1];
    const float* W1   = (const float*)d_in[2];
    const float* b1   = (const float*)d_in[3];
    const float* W2   = (const float*)d_in[4];
    const float* b2   = (const float*)d_in[5];
    const float* W3   = (const float*)d_in[6];
    const float* b3   = (const float*)d_in[7];
    float* out = (float*)d_out;

    binsort_kernel<<<BATCH, 1024, 0, stream>>>(xyz, out);
    fps_kernel<<<BATCH, 1024, 0, stream>>>(xyz, out);
    ballq_kernel<<<dim3(NPOINT / 4, BATCH), 256, 0, stream>>>(xyz, out);
    mlp_kernel<<<dim3(NPOINT, BATCH), 256, 0, stream>>>(xyz, feat, W1, b1, W2, b2, W3, b3, out);
}

// Round 7
// 3063.332 us; speedup vs baseline: 2.0170x; 2.0170x over previous
//
#include <hip/hip_runtime.h>
#include <cstdint>

#define BATCH   4
#define NPTS    16384
#define NCH     64
#define NPOINT  2048
#define NSAMP   32

// output layout (floats), concatenated in reference return order
#define OFF_XYZ  0                                 // new_xyz      (B,S,3)
#define OFF_IDX1 (BATCH*NPOINT*3)                  // new_xyz_idx  (B,S)    as float
#define OFF_FEAT (OFF_IDX1 + BATCH*NPOINT)         // new_features (B,128,S)
#define OFF_IDX3 (OFF_FEAT + BATCH*128*NPOINT)     // idx          (B,S,32) as float

// Scratch for sorted points lives in the new_features region of d_out
// (1,048,576 floats); mlp_kernel fully overwrites it afterwards.

// Exact float32 squared distance in numpy's evaluation order.
__device__ __forceinline__ float sqd_exact(float dx, float dy, float dz) {
    float a = __fmul_rn(dx, dx);
    float b = __fmul_rn(dy, dy);
    float c = __fmul_rn(dz, dz);
    return __fadd_rn(__fadd_rn(a, b), c);
}

__device__ __forceinline__ int part3(int v) {
    return (v & 1) | ((v & 2) << 2) | ((v & 4) << 4) | ((v & 8) << 6);
}

// Wave64 max of a NONNEGATIVE float via DPP (no LDS). Result broadcast via
// readlane(63). old=0 is the identity since all inputs are >= 0.
// (Validated bit-exact in rounds 4/5: absmax 0.)
__device__ __forceinline__ float wave_max_nonneg(float x) {
    int v;
    v = __builtin_amdgcn_update_dpp(0, __float_as_int(x), 0x111, 0xf, 0xf, false); // row_shr:1
    x = fmaxf(x, __int_as_float(v));
    v = __builtin_amdgcn_update_dpp(0, __float_as_int(x), 0x112, 0xf, 0xf, false); // row_shr:2
    x = fmaxf(x, __int_as_float(v));
    v = __builtin_amdgcn_update_dpp(0, __float_as_int(x), 0x114, 0xf, 0xf, false); // row_shr:4
    x = fmaxf(x, __int_as_float(v));
    v = __builtin_amdgcn_update_dpp(0, __float_as_int(x), 0x118, 0xf, 0xf, false); // row_shr:8
    x = fmaxf(x, __int_as_float(v));
    v = __builtin_amdgcn_update_dpp(0, __float_as_int(x), 0x142, 0xa, 0xf, false); // row_bcast:15
    x = fmaxf(x, __int_as_float(v));
    v = __builtin_amdgcn_update_dpp(0, __float_as_int(x), 0x143, 0xc, 0xf, false); // row_bcast:31
    x = fmaxf(x, __int_as_float(v));
    return __int_as_float(__builtin_amdgcn_readlane(__float_as_int(x), 63));
}

// Wave64 max of a u64 key held as (hi,lo) u32 pair, via DPP (no LDS).
// Same 6-stage pattern as wave_max_nonneg; identity (0,0) is correct since
// keys are nonnegative-distance bits. Result broadcast via readlane(63).
__device__ __forceinline__ unsigned long long wave_max_u64(unsigned hi, unsigned lo) {
#define STAGE(ctrl, rmask)                                                      \
    {                                                                           \
        unsigned ohi = (unsigned)__builtin_amdgcn_update_dpp(0, (int)hi, ctrl, rmask, 0xf, false); \
        unsigned olo = (unsigned)__builtin_amdgcn_update_dpp(0, (int)lo, ctrl, rmask, 0xf, false); \
        bool take = (ohi > hi) || ((ohi == hi) & (olo > lo));                   \
        hi = take ? ohi : hi;                                                   \
        lo = take ? olo : lo;                                                   \
    }
    STAGE(0x111, 0xf)   // row_shr:1
    STAGE(0x112, 0xf)   // row_shr:2
    STAGE(0x114, 0xf)   // row_shr:4
    STAGE(0x118, 0xf)   // row_shr:8
    STAGE(0x142, 0xa)   // row_bcast:15
    STAGE(0x143, 0xc)   // row_bcast:31
#undef STAGE
    unsigned rhi = (unsigned)__builtin_amdgcn_readlane((int)hi, 63);
    unsigned rlo = (unsigned)__builtin_amdgcn_readlane((int)lo, 63);
    return ((unsigned long long)rhi << 32) | rlo;
}

// ---------------------------------------------------------------------------
// Kernel 0: Morton-bin counting sort (per batch).
// ---------------------------------------------------------------------------
__global__ __launch_bounds__(1024)
void binsort_kernel(const float* __restrict__ xyz, float* __restrict__ out) {
    const int b = blockIdx.x, t = threadIdx.x, lane = t & 63, wv = t >> 6;
    float* scr  = out + OFF_FEAT;
    float* sx   = scr + (size_t)b * NPTS;
    float* sy   = scr + (size_t)(BATCH + b) * NPTS;
    float* sz   = scr + (size_t)(2 * BATCH + b) * NPTS;
    int*   sidx = (int*)(scr + (size_t)3 * BATCH * NPTS) + (size_t)b * NPTS;
    const float* xb = xyz + (size_t)b * (NPTS * 3);

    __shared__ int hist[4096];
    __shared__ int wsum[16];
    for (int k = t; k < 4096; k += 1024) hist[k] = 0;
    __syncthreads();

    const int base = t << 4;
    float f[48];
    {
        const float4* v4 = (const float4*)(xb + (size_t)base * 3);
#pragma unroll
        for (int q = 0; q < 12; ++q) {
            float4 v = v4[q];
            f[4*q+0] = v.x; f[4*q+1] = v.y; f[4*q+2] = v.z; f[4*q+3] = v.w;
        }
    }
    int cells[16];
    const float sc = 16.0f / 9.0f;
#pragma unroll
    for (int j = 0; j < 16; ++j) {
        int qx = (int)fminf(fmaxf((f[3*j+0] + 4.5f) * sc, 0.0f), 15.0f);
        int qy = (int)fminf(fmaxf((f[3*j+1] + 4.5f) * sc, 0.0f), 15.0f);
        int qz = (int)fminf(fmaxf((f[3*j+2] + 4.5f) * sc, 0.0f), 15.0f);
        cells[j] = part3(qx) | (part3(qy) << 1) | (part3(qz) << 2);
        atomicAdd(&hist[cells[j]], 1);
    }
    __syncthreads();

    int h0 = hist[4*t], h1 = hist[4*t+1], h2 = hist[4*t+2], h3 = hist[4*t+3];
    int s = h0 + h1 + h2 + h3;
    int ps = s;
#pragma unroll
    for (int off = 1; off <= 32; off <<= 1) {
        int o = __shfl_up(ps, off, 64);
        if (lane >= off) ps += o;
    }
    if (lane == 63) wsum[wv] = ps;
    __syncthreads();
    int wbase = 0;
    for (int w = 0; w < wv; ++w) wbase += wsum[w];
    int excl = wbase + ps - s;
    hist[4*t]   = excl;
    hist[4*t+1] = excl + h0;
    hist[4*t+2] = excl + h0 + h1;
    hist[4*t+3] = excl + h0 + h1 + h2;
    __syncthreads();

#pragma unroll
    for (int j = 0; j < 16; ++j) {
        int pos = atomicAdd(&hist[cells[j]], 1);
        sx[pos] = f[3*j+0]; sy[pos] = f[3*j+1]; sz[pos] = f[3*j+2];
        sidx[pos] = base + j;
    }
}

// ---------------------------------------------------------------------------
// Kernel 1: exact bucket-pruned FPS. R5 structure (best: 2631 us) with ONE
// change: the post-barrier 16 x ds_read_b64 scalar scan is replaced by a
// single lane-indexed ds_read_b64 + DPP u64 wave-max (VALU, parallel across
// SIMDs). Update loop / mk packing / leader election / global center load
// are R5-byte-identical. RULE (R4/R6 lesson): px/py/pz/dist are referenced
// ONLY inside the update loop — anything else spills them to scratch.
// ---------------------------------------------------------------------------
__global__ __launch_bounds__(1024)
void fps_kernel(const float* __restrict__ xyz, float* __restrict__ out) {
    const int b = blockIdx.x, t = threadIdx.x, lane = t & 63, wv = t >> 6;
    const float* scr  = out + OFF_FEAT;
    const float* sxp  = scr + (size_t)b * NPTS;
    const float* syp  = scr + (size_t)(BATCH + b) * NPTS;
    const float* szp  = scr + (size_t)(2 * BATCH + b) * NPTS;
    const int*   sip  = (const int*)(scr + (size_t)3 * BATCH * NPTS) + (size_t)b * NPTS;
    const float* __restrict__ xb = xyz + (size_t)b * (NPTS * 3);
    float* oxyz = out + OFF_XYZ  + (size_t)b * (NPOINT * 3);
    float* oidx = out + OFF_IDX1 + (size_t)b * NPOINT;

    const int base = t << 4;
    float px[16], py[16], pz[16], dist[16];
    unsigned idx2[8];
    {
        const float4* vx = (const float4*)(sxp + base);
        const float4* vy = (const float4*)(syp + base);
        const float4* vz = (const float4*)(szp + base);
        const int4*   vi = (const int4*)(sip + base);
#pragma unroll
        for (int q = 0; q < 4; ++q) {
            float4 a = vx[q]; px[4*q] = a.x; px[4*q+1] = a.y; px[4*q+2] = a.z; px[4*q+3] = a.w;
            float4 c = vy[q]; py[4*q] = c.x; py[4*q+1] = c.y; py[4*q+2] = c.z; py[4*q+3] = c.w;
            float4 d = vz[q]; pz[4*q] = d.x; pz[4*q+1] = d.y; pz[4*q+2] = d.z; pz[4*q+3] = d.w;
            int4   i = vi[q];
            idx2[2*q]   = (unsigned)i.x | ((unsigned)i.y << 16);
            idx2[2*q+1] = (unsigned)i.z | ((unsigned)i.w << 16);
        }
    }
    float bnx = px[0], bxx = px[0], bny = py[0], bxy = py[0], bnz = pz[0], bxz = pz[0];
#pragma unroll
    for (int j = 1; j < 16; ++j) {
        bnx = fminf(bnx, px[j]); bxx = fmaxf(bxx, px[j]);
        bny = fminf(bny, py[j]); bxy = fmaxf(bxy, py[j]);
        bnz = fminf(bnz, pz[j]); bxz = fmaxf(bxz, pz[j]);
    }
#pragma unroll
    for (int j = 0; j < 16; ++j) dist[j] = 1e10f;
    unsigned long long mk = 0;      // recomputed at it=1 (all buckets active then)
    float maxdG = 1e10f;

    __shared__ unsigned long long s_k[2][16];

    float cx = xb[0], cy = xb[1], cz = xb[2];
    if (t == 0) { oxyz[0] = cx; oxyz[1] = cy; oxyz[2] = cz; oidx[0] = 0.0f; }

    for (int it = 1; it < NPOINT; ++it) {
        const int q = it & 1;
        float dxl = fmaxf(fmaxf(bnx - cx, cx - bxx), 0.0f);
        float dyl = fmaxf(fmaxf(bny - cy, cy - bxy), 0.0f);
        float dzl = fmaxf(fmaxf(bnz - cz, cz - bxz), 0.0f);
        float bb  = dxl * dxl + dyl * dyl + dzl * dzl;
        if (bb * 0.99999f < maxdG) {          // bucket must update (exact test)
            float mv = 0.0f;
#pragma unroll
            for (int j = 0; j < 16; ++j) {
                float d  = sqd_exact(__fsub_rn(px[j], cx),
                                     __fsub_rn(py[j], cy),
                                     __fsub_rn(pz[j], cz));
                float nd = fminf(dist[j], d);
                dist[j] = nd;
                mv = fmaxf(mv, nd);
            }
            int bi = 0xFFFF;                  // min orig idx among value-ties
#pragma unroll
            for (int j = 0; j < 16; ++j) {
                int oi = (int)((idx2[j >> 1] >> ((j & 1) * 16)) & 0xFFFFu);
                if (dist[j] == mv) bi = min(bi, oi);
            }
            mk = ((unsigned long long)__float_as_uint(mv) << 32) | (unsigned)(~bi);
            maxdG = mv;
        }
        // wave max via DPP (VALU only) + ballot leader election
        float wm = wave_max_nonneg(maxdG);
        bool cand = (maxdG == wm);
        unsigned long long msk = __ballot(cand);
        if (__popcll(msk) > 1) {              // exact rare in-wave tie path
            unsigned long long best = 0;
            unsigned long long m2 = msk;
            while (m2) {
                int l = __ffsll(m2) - 1;
                unsigned long long omk = __shfl(mk, l, 64);
                best = best > omk ? best : omk;    // max mk == min orig idx
                m2 &= m2 - 1;
            }
            cand = cand && (mk == best);      // mk unique -> unique leader
        }
        if (cand) s_k[q][wv] = mk;
        __syncthreads();
        // each lane: ONE b64 read (16 distinct addrs, 4-way broadcast),
        // then DPP u64 wave-max -> every lane holds the global winner key.
        unsigned long long kv = s_k[q][lane & 15];
        unsigned long long gk = wave_max_u64((unsigned)(kv >> 32), (unsigned)kv);
        const int gi = (int)(~(unsigned)gk);  // orig index in [0,16384)
        cx = xb[gi*3+0]; cy = xb[gi*3+1]; cz = xb[gi*3+2];
        if (t == 0) {
            oxyz[it*3+0] = cx; oxyz[it*3+1] = cy; oxyz[it*3+2] = cz;
            oidx[it] = (float)gi;
        }
    }
}

// ---------------------------------------------------------------------------
// Kernel 2: ball query (unchanged).
// ---------------------------------------------------------------------------
__global__ __launch_bounds__(256)
void ballq_kernel(const float* __restrict__ xyz, float* __restrict__ out) {
    const int b    = blockIdx.y;
    const int t    = threadIdx.x;
    const int lane = t & 63;
    const int wv   = t >> 6;
    const int s    = blockIdx.x * 4 + wv;
    const float* __restrict__ xb = xyz + (size_t)b * (NPTS * 3);

    const float* ctr = out + OFF_XYZ + ((size_t)(b * NPOINT + s)) * 3;
    const float cx = ctr[0], cy = ctr[1], cz = ctr[2];

    __shared__ float sx[256], sy[256], sz[256];
    __shared__ int   lists[4][NSAMP];

    int have = 0;
    for (int tile = 0; tile < NPTS / 256; ++tile) {
        const int pi = tile * 256 + t;
        const float* p = xb + (size_t)pi * 3;
        float ax = p[0], ay = p[1], az = p[2];
        sx[t] = ax; sy[t] = ay; sz[t] = az;
        __syncthreads();
        if (have < NSAMP) {
#pragma unroll
            for (int sub = 0; sub < 4; ++sub) {
                const int li = sub * 64 + lane;
                float d2 = sqd_exact(__fsub_rn(cx, sx[li]),
                                     __fsub_rn(cy, sy[li]),
                                     __fsub_rn(cz, sz[li]));
                bool hit = d2 < 0.04f;
                unsigned long long m = __ballot(hit);
                if (hit) {
                    int pos = have + (int)__popcll(m & ((1ull << lane) - 1ull));
                    if (pos < NSAMP) lists[wv][pos] = tile * 256 + li;
                }
                have += (int)__popcll(m);
                if (have >= NSAMP) break;
            }
        }
        __syncthreads();
    }
    if (lane < NSAMP) {
        int hv = have < NSAMP ? have : NSAMP;
        int v0 = (have > 0) ? lists[wv][0] : 0;
        int v  = (lane < hv) ? lists[wv][lane] : v0;
        out[OFF_IDX3 + ((size_t)(b * NPOINT + s)) * NSAMP + lane] = (float)v;
    }
}

// ---------------------------------------------------------------------------
// Kernel 3: gather + 3-layer MLP + max over samples (unchanged).
// ---------------------------------------------------------------------------
__global__ __launch_bounds__(256)
void mlp_kernel(const float* __restrict__ xyz, const float* __restrict__ feat,
                const float* __restrict__ W1, const float* __restrict__ b1,
                const float* __restrict__ W2, const float* __restrict__ b2,
                const float* __restrict__ W3, const float* __restrict__ b3,
                float* __restrict__ out) {
    const int s = blockIdx.x;
    const int b = blockIdx.y;
    const int t = threadIdx.x;

    __shared__ __align__(16) float Wbuf[64 * 128];
    __shared__ float Xs[67 * 32];
    __shared__ float H1[64 * 32];
    __shared__ float H2[64 * 32];
    __shared__ int   idxs[NSAMP];
    __shared__ float ctr[3];

    if (t < NSAMP) idxs[t] = (int)out[OFF_IDX3 + ((size_t)(b * NPOINT + s)) * NSAMP + t];
    if (t < 3)     ctr[t]  = out[OFF_XYZ + ((size_t)(b * NPOINT + s)) * 3 + t];
    for (int k = t; k < 67 * 64; k += 256) {
        int i = k >> 6, o = k & 63;
        Wbuf[k] = W1[o * 67 + i];
    }
    __syncthreads();

    const float* xb = xyz  + (size_t)b * (NPTS * 3);
    const float* fb = feat + (size_t)b * (NCH * NPTS);
    for (int k = t; k < 67 * 32; k += 256) {
        int i = k >> 5, n = k & 31;
        int ii = idxs[n];
        float v;
        if (i < 3) v = __fsub_rn(xb[(size_t)ii * 3 + i], ctr[i]);
        else       v = fb[(size_t)(i - 3) * NPTS + ii];
        Xs[k] = v;
    }
    __syncthreads();

    const int n  = t & 31;
    const int og = t >> 5;

    {
        const int o0 = og * 8;
        float acc[8] = {0,0,0,0,0,0,0,0};
        for (int i = 0; i < 67; ++i) {
            float x = Xs[i * 32 + n];
            const float4* wp = (const float4*)&Wbuf[i * 64 + o0];
            float4 w0 = wp[0], w1 = wp[1];
            acc[0] += w0.x * x; acc[1] += w0.y * x; acc[2] += w0.z * x; acc[3] += w0.w * x;
            acc[4] += w1.x * x; acc[5] += w1.y * x; acc[6] += w1.z * x; acc[7] += w1.w * x;
        }
#pragma unroll
        for (int k = 0; k < 8; ++k)
            H1[(o0 + k) * 32 + n] = fmaxf(acc[k] + b1[o0 + k], 0.0f);
    }
    __syncthreads();
    for (int k = t; k < 64 * 64; k += 256) {
        int i = k >> 6, o = k & 63;
        Wbuf[k] = W2[o * 64 + i];
    }
    __syncthreads();

    {
        const int o0 = og * 8;
        float acc[8] = {0,0,0,0,0,0,0,0};
        for (int i = 0; i < 64; ++i) {
            float x = H1[i * 32 + n];
            const float4* wp = (const float4*)&Wbuf[i * 64 + o0];
            float4 w0 = wp[0], w1 = wp[1];
            acc[0] += w0.x * x; acc[1] += w0.y * x; acc[2] += w0.z * x; acc[3] += w0.w * x;
            acc[4] += w1.x * x; acc[5] += w1.y * x; acc[6] += w1.z * x; acc[7] += w1.w * x;
        }
#pragma unroll
        for (int k = 0; k < 8; ++k)
            H2[(o0 + k) * 32 + n] = fmaxf(acc[k] + b2[o0 + k], 0.0f);
    }
    __syncthreads();
    for (int k = t; k < 64 * 128; k += 256) {
        int i = k >> 7, o = k & 127;
        Wbuf[k] = W3[o * 64 + i];
    }
    __syncthreads();

    {
        const int o0 = og * 16;
        float acc[16];
#pragma unroll
        for (int k = 0; k < 16; ++k) acc[k] = 0.0f;
        for (int i = 0; i < 64; ++i) {
            float x = H2[i * 32 + n];
            const float4* wp = (const float4*)&Wbuf[i * 128 + o0];
            float4 w0 = wp[0], w1 = wp[1], w2 = wp[2], w3 = wp[3];
            acc[0]  += w0.x * x; acc[1]  += w0.y * x; acc[2]  += w0.z * x; acc[3]  += w0.w * x;
            acc[4]  += w1.x * x; acc[5]  += w1.y * x; acc[6]  += w1.z * x; acc[7]  += w1.w * x;
            acc[8]  += w2.x * x; acc[9]  += w2.y * x; acc[10] += w2.z * x; acc[11] += w2.w * x;
            acc[12] += w3.x * x; acc[13] += w3.y * x; acc[14] += w3.z * x; acc[15] += w3.w * x;
        }
#pragma unroll
        for (int k = 0; k < 16; ++k) {
            float h = fmaxf(acc[k] + b3[o0 + k], 0.0f);
#pragma unroll
            for (int off = 16; off >= 1; off >>= 1)
                h = fmaxf(h, __shfl_xor(h, off, 64));
            if (n == 0)
                out[OFF_FEAT + (size_t)b * 128 * NPOINT + (size_t)(o0 + k) * NPOINT + s] = h;
        }
    }
}

extern "C" void kernel_launch(void* const* d_in, const int* in_sizes, int n_in,
                              void* d_out, int out_size, void* d_ws, size_t ws_size,
                              hipStream_t stream) {
    const float* xyz  = (const float*)d_in[0];
    const float* feat = (const float*)d_in[1];
    const float* W1   = (const float*)d_in[2];
    const float* b1   = (const float*)d_in[3];
    const float* W2   = (const float*)d_in[4];
    const float* b2   = (const float*)d_in[5];
    const float* W3   = (const float*)d_in[6];
    const float* b3   = (const float*)d_in[7];
    float* out = (float*)d_out;

    binsort_kernel<<<BATCH, 1024, 0, stream>>>(xyz, out);
    fps_kernel<<<BATCH, 1024, 0, stream>>>(xyz, out);
    ballq_kernel<<<dim3(NPOINT / 4, BATCH), 256, 0, stream>>>(xyz, out);
    mlp_kernel<<<dim3(NPOINT, BATCH), 256, 0, stream>>>(xyz, feat, W1, b1, W2, b2, W3, b3, out);
}